// Round 1
// baseline (1423.047 us; speedup 1.0000x reference)
//
#include <hip/hip_runtime.h>
#include <math.h>

#define N_NODES 100000
#define N_EDGES 1000000
#define NPAIR 32
#define CUTOFF 6.0f

__global__ __launch_bounds__(256) void zero_out_kernel(float* __restrict__ out, int n) {
    int idx = blockIdx.x * blockDim.x + threadIdx.x;
    int stride = gridDim.x * blockDim.x;
    for (int k = idx; k < n; k += stride) out[k] = 0.0f;
}

__global__ __launch_bounds__(256) void g2_edge_kernel(
    const float* __restrict__ pos,        // [N,3]
    const float* __restrict__ cell,       // [G,3,3]
    const float* __restrict__ shift,      // [E,3]
    const float* __restrict__ etas,       // [32]
    const float* __restrict__ offs,       // [32]
    const int*   __restrict__ z,          // [N]
    const int*   __restrict__ ei,         // [2,E]
    const int*   __restrict__ batch,      // [N]
    float* __restrict__ out)              // [3*32, N]
{
    int e = blockIdx.x * blockDim.x + threadIdx.x;
    if (e >= N_EDGES) return;

    int i = ei[e];             // receiver
    int j = ei[N_EDGES + e];   // sender

    float sx = shift[3 * e + 0];
    float sy = shift[3 * e + 1];
    float sz = shift[3 * e + 2];

    int b = batch[i];
    const float* C = cell + 9 * b;   // tiny, L1/L2-resident

    float pix = pos[3 * i + 0], piy = pos[3 * i + 1], piz = pos[3 * i + 2];
    float pjx = pos[3 * j + 0], pjy = pos[3 * j + 1], pjz = pos[3 * j + 2];

    // vec = pos[j] - pos[i] + shift @ cell[batch[i]]   (row-vector x matrix)
    float vx = pjx - pix + sx * C[0] + sy * C[3] + sz * C[6];
    float vy = pjy - piy + sx * C[1] + sy * C[4] + sz * C[7];
    float vz = pjz - piz + sx * C[2] + sy * C[5] + sz * C[8];

    float r = sqrtf(vx * vx + vy * vy + vz * vz);
    if (r >= CUTOFF) return;   // fc == 0 exactly

    float fc = 0.5f * (__cosf(r * (float)(M_PI / 6.0)) + 1.0f);

    int zj = z[j];
    float* o = out + (size_t)zj * NPAIR * N_NODES + i;

    const float inv_c2 = 1.0f / (CUTOFF * CUTOFF);
#pragma unroll
    for (int p = 0; p < NPAIR; ++p) {
        float d = r - offs[p];
        float g = __expf(-etas[p] * d * d * inv_c2) * fc;
        atomicAdd(o + (size_t)p * N_NODES, g);
    }
}

extern "C" void kernel_launch(void* const* d_in, const int* in_sizes, int n_in,
                              void* d_out, int out_size, void* d_ws, size_t ws_size,
                              hipStream_t stream) {
    const float* pos   = (const float*)d_in[0];
    const float* cell  = (const float*)d_in[1];
    const float* shift = (const float*)d_in[2];
    const float* etas  = (const float*)d_in[3];
    const float* offs  = (const float*)d_in[4];
    const int*   z     = (const int*)d_in[5];
    const int*   ei    = (const int*)d_in[6];
    const int*   batch = (const int*)d_in[7];
    float* out = (float*)d_out;

    zero_out_kernel<<<2048, 256, 0, stream>>>(out, out_size);

    int blocks = (N_EDGES + 255) / 256;
    g2_edge_kernel<<<blocks, 256, 0, stream>>>(pos, cell, shift, etas, offs,
                                               z, ei, batch, out);
}

// Round 2
// 151.519 us; speedup vs baseline: 9.3919x; 9.3919x over previous
//
#include <hip/hip_runtime.h>
#include <math.h>

#define N_NODES 100000
#define N_EDGES 1000000
#define NPAIR 32
#define CUTOFF 6.0f
#define SCAN_CHUNK 1024
#define NBLK ((N_NODES + SCAN_CHUNK - 1) / SCAN_CHUNK)   // 98

// ---------- pass 1: per-edge r + species pack, per-node valid count ----------
__global__ __launch_bounds__(256) void count_kernel(
    const float* __restrict__ pos,        // [N,3]
    const float* __restrict__ cell,       // [G,3,3]
    const float* __restrict__ shift,      // [E,3]
    const int*   __restrict__ z,          // [N]
    const int*   __restrict__ ei,         // [2,E]
    const int*   __restrict__ batch,      // [N]
    unsigned int* __restrict__ rec,       // [E] packed (r | zj)
    int*          __restrict__ cnt)       // [N]
{
    int e = blockIdx.x * blockDim.x + threadIdx.x;
    if (e >= N_EDGES) return;

    int i = ei[e];
    int j = ei[N_EDGES + e];

    float sx = shift[3 * e + 0];
    float sy = shift[3 * e + 1];
    float sz = shift[3 * e + 2];

    const float* C = cell + 9 * batch[i];

    float vx = pos[3 * j + 0] - pos[3 * i + 0] + sx * C[0] + sy * C[3] + sz * C[6];
    float vy = pos[3 * j + 1] - pos[3 * i + 1] + sx * C[1] + sy * C[4] + sz * C[7];
    float vz = pos[3 * j + 2] - pos[3 * i + 2] + sx * C[2] + sy * C[5] + sz * C[8];

    float r = sqrtf(vx * vx + vy * vy + vz * vz);

    if (r < CUTOFF) {
        // pack species into 2 low mantissa bits of r (<=2^-22 rel perturbation)
        unsigned int pr = (__float_as_uint(r) & 0xFFFFFFFCu) | (unsigned int)(z[j] & 3);
        rec[e] = pr;
        atomicAdd(&cnt[i], 1);
    } else {
        rec[e] = 0xFFFFFFFFu;   // sentinel (never a valid packed r: r>=0, r<6)
    }
}

// ---------- scan step a: per-block partial sums ----------
__global__ __launch_bounds__(256) void scan_bsums_kernel(
    const int* __restrict__ cnt, int* __restrict__ bsum)
{
    __shared__ int s[256];
    int t = threadIdx.x;
    int base = blockIdx.x * SCAN_CHUNK + t * 4;
    int sum = 0;
#pragma unroll
    for (int q = 0; q < 4; ++q) {
        int idx = base + q;
        if (idx < N_NODES) sum += cnt[idx];
    }
    s[t] = sum;
    __syncthreads();
    for (int d = 128; d > 0; d >>= 1) {
        if (t < d) s[t] += s[t + d];
        __syncthreads();
    }
    if (t == 0) bsum[blockIdx.x] = s[0];
}

// ---------- scan step b: exclusive scan of block sums (NBLK<=128) ----------
__global__ __launch_bounds__(128) void scan_boff_kernel(
    const int* __restrict__ bsum, int* __restrict__ boff)
{
    __shared__ int s[128];
    int t = threadIdx.x;
    int v = (t < NBLK) ? bsum[t] : 0;
    s[t] = v;
    __syncthreads();
    for (int d = 1; d < 128; d <<= 1) {
        int u = (t >= d) ? s[t - d] : 0;
        __syncthreads();
        s[t] += u;
        __syncthreads();
    }
    if (t < NBLK) boff[t] = s[t] - v;   // exclusive
}

// ---------- scan step c: full exclusive scan -> off[N+1] ----------
__global__ __launch_bounds__(256) void scan_off_kernel(
    const int* __restrict__ cnt, const int* __restrict__ boff,
    int* __restrict__ off)
{
    __shared__ int s[256];
    int t = threadIdx.x;
    int base = blockIdx.x * SCAN_CHUNK + t * 4;

    int c[4];
    int tsum = 0;
#pragma unroll
    for (int q = 0; q < 4; ++q) {
        int idx = base + q;
        c[q] = (idx < N_NODES) ? cnt[idx] : 0;
        tsum += c[q];
    }
    s[t] = tsum;
    __syncthreads();
    for (int d = 1; d < 256; d <<= 1) {
        int u = (t >= d) ? s[t - d] : 0;
        __syncthreads();
        s[t] += u;
        __syncthreads();
    }
    int texcl = s[t] - tsum + boff[blockIdx.x];

    int run = 0;
#pragma unroll
    for (int q = 0; q < 4; ++q) {
        int idx = base + q;
        if (idx < N_NODES) {
            off[idx] = texcl + run;
            if (idx == N_NODES - 1) off[N_NODES] = texcl + run + c[q];
        }
        run += c[q];
    }
}

// ---------- pass 2: scatter packed records into CSR slots ----------
__global__ __launch_bounds__(256) void scatter_kernel(
    const unsigned int* __restrict__ rec,
    const int*          __restrict__ ei,
    int*                __restrict__ cur,   // cursor, initialized to off[0..N)
    unsigned int*       __restrict__ srec)
{
    int e = blockIdx.x * blockDim.x + threadIdx.x;
    if (e >= N_EDGES) return;
    unsigned int rc = rec[e];
    if (rc != 0xFFFFFFFFu) {
        int i = ei[e];
        int slot = atomicAdd(&cur[i], 1);
        srec[slot] = rc;
    }
}

// ---------- pass 3: per-node register accumulation, single output write ----------
__global__ __launch_bounds__(256) void accum_kernel(
    const unsigned int* __restrict__ srec,
    const int*          __restrict__ off,
    const float*        __restrict__ etas,   // [32]
    const float*        __restrict__ offs,   // [32]
    float*              __restrict__ out)    // [96, N]
{
    int n = blockIdx.x * blockDim.x + threadIdx.x;
    if (n >= N_NODES) return;

    float a0[NPAIR], a1[NPAIR], a2[NPAIR];
#pragma unroll
    for (int p = 0; p < NPAIR; ++p) { a0[p] = 0.0f; a1[p] = 0.0f; a2[p] = 0.0f; }

    int s = off[n];
    int epos = off[n + 1];
    const float inv_c2 = 1.0f / (CUTOFF * CUTOFF);

    for (int k = s; k < epos; ++k) {
        unsigned int rc = srec[k];
        int zj = rc & 3;
        float r = __uint_as_float(rc & 0xFFFFFFFCu);
        float fc = 0.5f * (__cosf(r * (float)(M_PI / 6.0)) + 1.0f);
        float m0 = (zj == 0) ? fc : 0.0f;
        float m1 = (zj == 1) ? fc : 0.0f;
        float m2 = (zj == 2) ? fc : 0.0f;
#pragma unroll
        for (int p = 0; p < NPAIR; ++p) {
            float d = r - offs[p];
            float g = __expf(-etas[p] * d * d * inv_c2);
            a0[p] = fmaf(m0, g, a0[p]);
            a1[p] = fmaf(m1, g, a1[p]);
            a2[p] = fmaf(m2, g, a2[p]);
        }
    }

#pragma unroll
    for (int p = 0; p < NPAIR; ++p) {
        out[(0 * NPAIR + p) * N_NODES + n] = a0[p];
        out[(1 * NPAIR + p) * N_NODES + n] = a1[p];
        out[(2 * NPAIR + p) * N_NODES + n] = a2[p];
    }
}

extern "C" void kernel_launch(void* const* d_in, const int* in_sizes, int n_in,
                              void* d_out, int out_size, void* d_ws, size_t ws_size,
                              hipStream_t stream) {
    const float* pos   = (const float*)d_in[0];
    const float* cell  = (const float*)d_in[1];
    const float* shift = (const float*)d_in[2];
    const float* etas  = (const float*)d_in[3];
    const float* offs  = (const float*)d_in[4];
    const int*   z     = (const int*)d_in[5];
    const int*   ei    = (const int*)d_in[6];
    const int*   batch = (const int*)d_in[7];
    float* out = (float*)d_out;

    char* ws = (char*)d_ws;
    unsigned int* rec  = (unsigned int*)(ws + 0);                 // 4,000,000 B
    unsigned int* srec = (unsigned int*)(ws + 4000000);           // 4,000,000 B
    int* cnt  = (int*)(ws + 8000000);                             // 400,000 B (reused as cursor)
    int* off  = (int*)(ws + 8400128);                             // 400,004 B
    int* bsum = (int*)(ws + 8800768);                             // 512 B
    int* boff = (int*)(ws + 8801280);                             // 512 B

    hipMemsetAsync(cnt, 0, N_NODES * sizeof(int), stream);

    int eblocks = (N_EDGES + 255) / 256;
    count_kernel<<<eblocks, 256, 0, stream>>>(pos, cell, shift, z, ei, batch, rec, cnt);

    scan_bsums_kernel<<<NBLK, 256, 0, stream>>>(cnt, bsum);
    scan_boff_kernel<<<1, 128, 0, stream>>>(bsum, boff);
    scan_off_kernel<<<NBLK, 256, 0, stream>>>(cnt, boff, off);

    // cursor = off[0..N)
    hipMemcpyAsync(cnt, off, N_NODES * sizeof(int), hipMemcpyDeviceToDevice, stream);

    scatter_kernel<<<eblocks, 256, 0, stream>>>(rec, ei, cnt, srec);

    int nblocks = (N_NODES + 255) / 256;
    accum_kernel<<<nblocks, 256, 0, stream>>>(srec, off, etas, offs, out);
}